// Round 1
// baseline (48.306 us; speedup 1.0000x reference)
//
#include <hip/hip_runtime.h>

#define B_ 16
#define U_ 500
#define S_ 256
#define H_ 128
#define UTILE 32
#define NWAVES 16
#define TPB (NWAVES * 64)

__global__ __launch_bounds__(TPB, 1) void attn_kernel(
    const float* __restrict__ user,     // (B,U,4)
    const float* __restrict__ server,   // (B,S,6)
    const int*   __restrict__ masks,    // (B,U,S) int32 0/1 OR packed bytes (auto-detected)
    const float* __restrict__ Wu,       // (3,H)
    const float* __restrict__ bu,       // (H)
    const float* __restrict__ Ws,       // (7,H)  (row 6 multiplies the zero 'active' col -> unused)
    const float* __restrict__ bs,       // (H)
    const float* __restrict__ W1,       // (H,H)
    const float* __restrict__ W2,       // (H,H)
    const float* __restrict__ vt,       // (H)
    float* __restrict__ out)            // (B,U,S) fp32
{
  __shared__ float E[H_][S_];          // 128 KB, transposed [h][s], holds exp(2*enc)
  __shared__ float M1s[6 * H_];        // Ws@W1 (rows 0..5)
  __shared__ float M2s[3 * H_];        // Wu@W2
  __shared__ float c1s[H_];            // bs@W1
  __shared__ float c2s[H_];            // bu@W2
  __shared__ float vts[H_];
  __shared__ float decs[NWAVES][2][H_]; // exp(2*dec) for each wave's two u-rows
  __shared__ float vsum_s;

  const int tid = threadIdx.x;
  const int bid = blockIdx.x;
  const int b   = bid >> 4;
  const int u0  = (bid & 15) * UTILE;

  // ---- phase 0: fused weight products (redundant per block, negligible) ----
  {
    const int h = tid & (H_ - 1);
    for (int job = tid >> 7; job < 11; job += 8) {
      const float* Lv; const float* Rm; float* dst;
      if (job < 6)       { Lv = Ws + job * H_;       Rm = W1; dst = M1s + job * H_; }
      else if (job == 6) { Lv = bs;                  Rm = W1; dst = c1s; }
      else if (job < 10) { Lv = Wu + (job - 7) * H_; Rm = W2; dst = M2s + (job - 7) * H_; }
      else               { Lv = bu;                  Rm = W2; dst = c2s; }
      float acc = 0.f;
      for (int j = 0; j < H_; ++j) acc = fmaf(Lv[j], Rm[j * H_ + h], acc);
      dst[h] = acc;
    }
    if (tid < H_) vts[tid] = vt[tid];
    if (tid < 64) {                       // vsum = sum(vt), from global (no LDS dep)
      float v = vt[tid] + vt[tid + 64];
      #pragma unroll
      for (int off = 32; off > 0; off >>= 1) v += __shfl_xor(v, off, 64);
      if (tid == 0) vsum_s = v;
    }
  }

  // ---- mask dtype detection: int32 masks are strictly 0/1; packed bools make words >1 ----
  int lflag;
  {
    int4 mw = *reinterpret_cast<const int4*>(masks + tid * 4);   // first 4096 words, in-bounds either way
    lflag = ((unsigned)mw.x > 1u) | ((unsigned)mw.y > 1u) |
            ((unsigned)mw.z > 1u) | ((unsigned)mw.w > 1u);
  }
  const int bytemode = __syncthreads_or(lflag);   // barrier also publishes phase-0 LDS

  // ---- phase 1: stage E[h][s] = exp(2*(c1[h] + sum_k server[b,s,k]*M1[k][h])) ----
  {
    const int s  = tid & (S_ - 1);
    const int h0 = tid >> 8;   // 0..3, wave-uniform
    const float2* sv = reinterpret_cast<const float2*>(server + ((size_t)b * S_ + s) * 6);
    const float2 p0 = sv[0], p1 = sv[1], p2 = sv[2];
    for (int h = h0; h < H_; h += 4) {
      float a = c1s[h];
      a = fmaf(p0.x, M1s[0 * H_ + h], a);
      a = fmaf(p0.y, M1s[1 * H_ + h], a);
      a = fmaf(p1.x, M1s[2 * H_ + h], a);
      a = fmaf(p1.y, M1s[3 * H_ + h], a);
      a = fmaf(p2.x, M1s[4 * H_ + h], a);
      a = fmaf(p2.y, M1s[5 * H_ + h], a);
      E[h][s] = __expf(fminf(fmaxf(a + a, -60.f), 60.f));
    }
  }

  const int w    = tid >> 6;
  const int lane = tid & 63;
  const int uA   = u0 + 2 * w;          // pairs are both-valid or both-invalid (U_ even, u0 even)
  const int uAc  = min(uA,     U_ - 1);
  const int uBc  = min(uA + 1, U_ - 1);

  // ---- dec rows for both u's: D = exp(2*dec). Same-wave LDS slot, no barrier needed for decs. ----
  {
    const float* uvA = user + ((size_t)b * U_ + uAc) * 4;
    const float* uvB = user + ((size_t)b * U_ + uBc) * 4;
    const float gA0 = uvA[0], gA1 = uvA[1], gA2 = uvA[2];
    const float gB0 = uvB[0], gB1 = uvB[1], gB2 = uvB[2];
    #pragma unroll
    for (int r = 0; r < 2; ++r) {
      const int h1 = lane, h2 = lane + 64;
      const float g0 = r ? gB0 : gA0, g1 = r ? gB1 : gA1, g2 = r ? gB2 : gA2;
      float a0 = c2s[h1];
      a0 = fmaf(g0, M2s[0 * H_ + h1], a0);
      a0 = fmaf(g1, M2s[1 * H_ + h1], a0);
      a0 = fmaf(g2, M2s[2 * H_ + h1], a0);
      decs[w][r][h1] = __expf(fminf(fmaxf(a0 + a0, -60.f), 60.f));
      float a1 = c2s[h2];
      a1 = fmaf(g0, M2s[0 * H_ + h2], a1);
      a1 = fmaf(g1, M2s[1 * H_ + h2], a1);
      a1 = fmaf(g2, M2s[2 * H_ + h2], a1);
      decs[w][r][h2] = __expf(fminf(fmaxf(a1 + a1, -60.f), 60.f));
    }
  }
  __syncthreads();   // publishes E (decs is same-wave, also covered)

  // ---- issue mask loads early to hide HBM latency under the main loop ----
  const size_t ridxA = ((size_t)b * U_ + uAc) * S_ + (size_t)lane * 4;
  const size_t ridxB = ((size_t)b * U_ + uBc) * S_ + (size_t)lane * 4;
  int mA0, mA1, mA2, mA3, mB0, mB1, mB2, mB3;
  if (!bytemode) {
    int4 mm = *reinterpret_cast<const int4*>(masks + ridxA);
    mA0 = mm.x; mA1 = mm.y; mA2 = mm.z; mA3 = mm.w;
    int4 nn = *reinterpret_cast<const int4*>(masks + ridxB);
    mB0 = nn.x; mB1 = nn.y; mB2 = nn.z; mB3 = nn.w;
  } else {
    const unsigned char* mb = reinterpret_cast<const unsigned char*>(masks);
    uchar4 mm = *reinterpret_cast<const uchar4*>(mb + ridxA);
    mA0 = mm.x; mA1 = mm.y; mA2 = mm.z; mA3 = mm.w;
    uchar4 nn = *reinterpret_cast<const uchar4*>(mb + ridxB);
    mB0 = nn.x; mB1 = nn.y; mB2 = nn.z; mB3 = nn.w;
  }

  // ---- main accumulation: lane l owns s = 4l..4l+3 for BOTH u-rows in one E pass ----
  // acc = sum_h v_h / (E_h*D_h + 1), computed 4 h at a time with ONE rcp:
  //   sum v_i/t_i = ((v0 t1 + v1 t0) t2 t3 + (v2 t3 + v3 t2) t0 t1) / (t0 t1 t2 t3)
  // Software-pipelined: two register banks (x,y); bank N+1's 7 LDS reads are issued
  // before bank N's 120-VALU compute so no wave sits in s_waitcnt lgkmcnt.
  float aA0 = 0.f, aA1 = 0.f, aA2 = 0.f, aA3 = 0.f;
  float aB0 = 0.f, aB1 = 0.f, aB2 = 0.f, aB3 = 0.f;
  const int l4 = lane * 4;

  auto quad = [](const float4& vv, float ea, float eb, float ec, float ed,
                 const float4& d, float& acc) {
    float t0 = fmaf(ea, d.x, 1.0f);
    float t1 = fmaf(eb, d.y, 1.0f);
    float t2 = fmaf(ec, d.z, 1.0f);
    float t3 = fmaf(ed, d.w, 1.0f);
    float t01 = t0 * t1;
    float t23 = t2 * t3;
    float n01 = fmaf(vv.x, t1, vv.y * t0);
    float n23 = fmaf(vv.z, t3, vv.w * t2);
    float den = t01 * t23;
    float num = fmaf(n01, t23, n23 * t01);
    acc = fmaf(num, __builtin_amdgcn_rcpf(den), acc);
  };

  float4 xe0, xe1, xe2, xe3, xdA, xdB, xv;
  float4 ye0, ye1, ye2, ye3, ydA, ydB, yv;

  auto load_bank = [&](int h, float4& f0, float4& f1, float4& f2, float4& f3,
                       float4& dA4, float4& dB4, float4& vv) {
    f0 = *reinterpret_cast<const float4*>(&E[h + 0][l4]);
    f1 = *reinterpret_cast<const float4*>(&E[h + 1][l4]);
    f2 = *reinterpret_cast<const float4*>(&E[h + 2][l4]);
    f3 = *reinterpret_cast<const float4*>(&E[h + 3][l4]);
    dA4 = *reinterpret_cast<const float4*>(&decs[w][0][h]);   // LDS broadcast
    dB4 = *reinterpret_cast<const float4*>(&decs[w][1][h]);   // LDS broadcast
    vv  = *reinterpret_cast<const float4*>(&vts[h]);          // LDS broadcast
  };

  auto compute_bank = [&](const float4& f0, const float4& f1, const float4& f2, const float4& f3,
                          const float4& dA4, const float4& dB4, const float4& vv) {
    quad(vv, f0.x, f1.x, f2.x, f3.x, dA4, aA0);
    quad(vv, f0.y, f1.y, f2.y, f3.y, dA4, aA1);
    quad(vv, f0.z, f1.z, f2.z, f3.z, dA4, aA2);
    quad(vv, f0.w, f1.w, f2.w, f3.w, dA4, aA3);
    quad(vv, f0.x, f1.x, f2.x, f3.x, dB4, aB0);
    quad(vv, f0.y, f1.y, f2.y, f3.y, dB4, aB1);
    quad(vv, f0.z, f1.z, f2.z, f3.z, dB4, aB2);
    quad(vv, f0.w, f1.w, f2.w, f3.w, dB4, aB3);
  };

  load_bank(0, xe0, xe1, xe2, xe3, xdA, xdB, xv);
  #pragma unroll 1   // keep the ping-pong body small (icache) — overlap comes from the 2 banks
  for (int it = 0; it < H_ / 4; it += 2) {
    load_bank((it + 1) << 2, ye0, ye1, ye2, ye3, ydA, ydB, yv);       // prefetch odd group
    compute_bank(xe0, xe1, xe2, xe3, xdA, xdB, xv);                   // compute even group
    load_bank((((it + 2) & 31)) << 2, xe0, xe1, xe2, xe3, xdA, xdB, xv); // prefetch next even (wraps harmlessly at end)
    compute_bank(ye0, ye1, ye2, ye3, ydA, ydB, yv);                   // compute odd group
  }

  // ---- mask + softmax + store (wave-uniform validity: both rows valid or both invalid) ----
  if (uA < U_) {
    const float negs = -103.6163291847321f * 10.0f;   // log(1e-45) * EXPLORATION_C
    const float vs10 = vsum_s * 10.0f;
    #pragma unroll
    for (int r = 0; r < 2; ++r) {
      const float b0 = r ? aB0 : aA0, b1 = r ? aB1 : aA1;
      const float b2 = r ? aB2 : aA2, b3 = r ? aB3 : aA3;
      const int   m0 = r ? mB0 : mA0, m1 = r ? mB1 : mA1;
      const int   m2 = r ? mB2 : mA2, m3 = r ? mB3 : mA3;
      float s0 = m0 ? fmaf(-20.0f, b0, vs10) : negs;
      float s1 = m1 ? fmaf(-20.0f, b1, vs10) : negs;
      float s2 = m2 ? fmaf(-20.0f, b2, vs10) : negs;
      float s3 = m3 ? fmaf(-20.0f, b3, vs10) : negs;
      float mx = fmaxf(fmaxf(s0, s1), fmaxf(s2, s3));
      #pragma unroll
      for (int off = 32; off > 0; off >>= 1) mx = fmaxf(mx, __shfl_xor(mx, off, 64));
      float p0 = __expf(s0 - mx);
      float p1 = __expf(s1 - mx);
      float p2 = __expf(s2 - mx);
      float p3 = __expf(s3 - mx);
      float sum = (p0 + p1) + (p2 + p3);
      #pragma unroll
      for (int off = 32; off > 0; off >>= 1) sum += __shfl_xor(sum, off, 64);
      const float inv = __builtin_amdgcn_rcpf(sum);
      float4 o;
      o.x = p0 * inv; o.y = p1 * inv; o.z = p2 * inv; o.w = p3 * inv;
      *reinterpret_cast<float4*>(out + (r ? ridxB : ridxA)) = o;
    }
  }
}

extern "C" void kernel_launch(void* const* d_in, const int* in_sizes, int n_in,
                              void* d_out, int out_size, void* d_ws, size_t ws_size,
                              hipStream_t stream) {
  const float* user   = (const float*)d_in[0];
  const float* server = (const float*)d_in[1];
  const int*   masks  = (const int*)d_in[2];
  const float* Wu = (const float*)d_in[3];
  const float* bu = (const float*)d_in[4];
  const float* Ws = (const float*)d_in[5];
  const float* bs = (const float*)d_in[6];
  const float* W1 = (const float*)d_in[7];
  const float* W2 = (const float*)d_in[8];
  const float* vt = (const float*)d_in[9];
  float* out = (float*)d_out;
  (void)in_sizes; (void)n_in; (void)out_size; (void)d_ws; (void)ws_size;

  attn_kernel<<<dim3(B_ * ((U_ + UTILE - 1) / UTILE)), dim3(TPB), 0, stream>>>(
      user, server, masks, Wu, bu, Ws, bs, W1, W2, vt, out);
}